// Round 1
// baseline (10427.219 us; speedup 1.0000x reference)
//
#include <hip/hip_runtime.h>
#include <hip/hip_bf16.h>

// GridNetBlock round-7. R6 post-mortem: k_inter_lstm (4.72ms of 7.0ms) was
// issue-bound scalar-FMA (MfmaUtil=0, VALUBusy 40%, 130/256 CUs, ~1250 VALU
// insts/thread/step + 786KB/step/block L2 weight refetch). R7: rewrite the
// inter LSTM on the matrix cores. 17 blocks x 512 thr, 16 seqs/block, M=16
// mfma_f32_16x16x32_bf16 over combined [x;h] (K=384) x W (N=1024). Weights
// pre-swizzled to B-fragment order (wave-contiguous 1KB L2 loads). A operand
// (x,h) kept at fp32-equivalent precision via bf16 hi+lo split (2 MFMA per
// shared B frag). Wave w owns gate cols [32w,32w+32) of all 4 gates -> gate
// nonlinearity + c-state fully in registers. A frags stored in LDS in
// fragment order (conflict-free ds_read_b128), double-buffered -> ONE
// __syncthreads per timestep. Fused Linear = 8 MFMA/wave from h frags.
// B=4 T=512 NF=65 C=128 NH=4 E=8 H=256 DOWN=4 L=100 VD=32.
//
// ws layout (bytes):
//  A [0,68.2M):        hc[16.8M]+yf[33.5M]  ->  ln1y -> Vh -> ph
//  B [68.2M,136.3M):   intra -> av
//  C [136.3M,204.5M):  inter
//  DE[204.5M,238.6M):  yr[33.5M] -> Qh[17M]+Kh[17M]
//  WT[238.6M,242.6M):  fp32 transposed intra weights + bf16 MFMA fragments

typedef unsigned short u16;
typedef unsigned int u32;

#define OFF_A    0ULL
#define OFF_B    68157440ULL
#define OFF_C    136314880ULL
#define OFF_DE   204472320ULL
#define OFF_WT   238551040ULL

typedef __attribute__((ext_vector_type(8))) short bf16x8;
typedef __attribute__((ext_vector_type(4))) float f32x4;

__device__ __forceinline__ float b2f(u16 u) {
  union { u32 i; float f; } v; v.i = ((u32)u) << 16; return v.f;
}
__device__ __forceinline__ u16 f2b(float f) {
  union { float f; u32 i; } v; v.f = f;
  u32 r = v.i + 0x7fffu + ((v.i >> 16) & 1u);
  return (u16)(r >> 16);
}
__device__ __forceinline__ float bflo(u32 u) {
  union { u32 i; float f; } v; v.i = u << 16; return v.f;
}
__device__ __forceinline__ float bfhi(u32 u) {
  union { u32 i; float f; } v; v.i = u & 0xffff0000u; return v.f;
}
__device__ __forceinline__ float sigf(float x) { return 1.f / (1.f + __expf(-x)); }
__device__ __forceinline__ float tanh_(float x) {
  float cx = fminf(15.f, fmaxf(-15.f, x));
  float e = __expf(2.f * cx);
  return (e - 1.f) / (e + 1.f);
}
__device__ __forceinline__ void wavered2(float& s, float& q) {
  #pragma unroll
  for (int o = 32; o > 0; o >>= 1) {
    s += __shfl_down(s, o, 64);
    q += __shfl_down(q, o, 64);
  }
}

// ---------------- transpose fp32 [R][K] -> fp32 [K][R] ----------------
__global__ void k_transpose_ff(const float* __restrict__ src, float* __restrict__ dst,
                               int R, int K) {
  int e = blockIdx.x * 256 + threadIdx.x;
  if (e >= R * K) return;
  int r = e / K, k = e - r * K;
  dst[k * R + r] = src[e];
}

// ---- build gate-weight MFMA B-fragments: W[k][n], k=[x(128);h(256)], n=1024
// frag layout: dst[((nt*12 + kc)*64 + lane)*8 + j] = bf16(W[kc*32+(lane>>4)*8+j][nt*16+(lane&15)])
__global__ void k_prep_gfrag(const float* __restrict__ wih, const float* __restrict__ whh,
                             u16* __restrict__ dst) {
  int idx = blockIdx.x * 256 + threadIdx.x;
  if (idx >= 393216) return;
  int j = idx & 7, l = (idx >> 3) & 63;
  int r3 = idx >> 9;              // nt*12 + kc
  int kc = r3 % 12, nt = r3 / 12;
  int k = kc * 32 + ((l >> 4) << 3) + j;
  int n = (nt << 4) + (l & 15);
  float v = k < 128 ? wih[(size_t)n * 128 + k] : whh[(size_t)n * 256 + (k - 128)];
  dst[idx] = f2b(v);
}

// ---- build lin-weight MFMA B-fragments: W[k=256][n=128] = lin_w[n][k]
__global__ void k_prep_lfrag(const float* __restrict__ lw, u16* __restrict__ dst) {
  int idx = blockIdx.x * 256 + threadIdx.x;
  if (idx >= 32768) return;
  int j = idx & 7, l = (idx >> 3) & 63;
  int r3 = idx >> 9;              // nt*8 + kc
  int kc = r3 & 7, nt = r3 >> 3;
  int k = kc * 32 + ((l >> 4) << 3) + j;
  int n = (nt << 4) + (l & 15);
  dst[idx] = f2b(lw[(size_t)n * 256 + k]);
}

// ---------------- conv(k=s=4) + bias + PReLU + LN(C) ----------------
__global__ __launch_bounds__(256) void k_conv_ln0(
    const float* __restrict__ x32, const float* __restrict__ cw,
    const float* __restrict__ cb, const float* __restrict__ ca,
    const float* __restrict__ g0, const float* __restrict__ b0,
    float* __restrict__ hc) {
  __shared__ float xs[8192];   // [64 freq][128 c]
  __shared__ float hs[2048];   // [16][128]
  __shared__ float mu_[16], ri_[16];
  int n = blockIdx.x, tid = threadIdx.x;
  const float4* xr = (const float4*)(x32 + (size_t)n * 8320);
  for (int e = tid; e < 2048; e += 256) ((float4*)xs)[e] = xr[e];
  __syncthreads();
  int g = tid >> 7, o = tid & 127;
  float a = ca[0];
  float cbv = cb[o];
  float acc[8];
  #pragma unroll
  for (int j = 0; j < 8; ++j) acc[j] = cbv;
  const float4* cw4 = (const float4*)cw;   // [o][c][4m]
  for (int c = 0; c < 128; ++c) {
    float4 w = cw4[o * 128 + c];
    #pragma unroll
    for (int j = 0; j < 8; ++j) {
      int i = 8 * g + j;
      const float* xi = &xs[i * 512 + c];
      acc[j] += w.x * xi[0] + w.y * xi[128] + w.z * xi[256] + w.w * xi[384];
    }
  }
  #pragma unroll
  for (int j = 0; j < 8; ++j) {
    int i = 8 * g + j;
    float v = acc[j];
    v = v >= 0.f ? v : a * v;
    hs[i * 128 + o] = v;
  }
  __syncthreads();
  if (tid < 16) {
    float s = 0.f, q = 0.f;
    for (int c = 0; c < 128; ++c) { float v = hs[tid * 128 + c]; s += v; q += v * v; }
    float mu = s / 128.f;
    mu_[tid] = mu;
    ri_[tid] = rsqrtf(fmaxf(q / 128.f - mu * mu, 0.f) + 1e-5f);
  }
  __syncthreads();
  float gg = g0[o], bb = b0[o];
  #pragma unroll
  for (int j = 0; j < 8; ++j) {
    int i = 8 * g + j;
    hc[((size_t)n * 16 + i) * 128 + o] = (hs[i * 128 + o] - mu_[i]) * ri_[i] * gg + bb;
  }
}

// ---------------- intra BiLSTM over freq (seq len 16) ----------------
__global__ __launch_bounds__(256) void k_intra_lstm(
    const float* __restrict__ hc,
    const float* __restrict__ wiTf, const float* __restrict__ whTf,
    const float* __restrict__ bihf, const float* __restrict__ bhhf,
    const float* __restrict__ wiTr, const float* __restrict__ whTr,
    const float* __restrict__ bihr, const float* __restrict__ bhhr,
    float* __restrict__ yf, float* __restrict__ yr) {
  __shared__ float xt[1024];    // [8][128]
  __shared__ float hsh[2048];   // [8][256]
  __shared__ float csh[2048];
  __shared__ float gbuf[8192];  // [8][1024]
  int tid = threadIdx.x;
  int grp = blockIdx.x & 255, dir = blockIdx.x >> 8;
  int n0 = grp * 8;
  const float4* wi4 = (const float4*)(dir ? wiTr : wiTf);
  const float4* wh4 = (const float4*)(dir ? whTr : whTf);
  const float* bi = dir ? bihr : bihf;
  const float* bh = dir ? bhhr : bhhf;
  float* yo = dir ? yr : yf;
  float bias[4];
  #pragma unroll
  for (int j = 0; j < 4; ++j) bias[j] = bi[4 * tid + j] + bh[4 * tid + j];
  for (int e = tid; e < 2048; e += 256) { hsh[e] = 0.f; csh[e] = 0.f; }
  for (int t = 0; t < 16; ++t) {
    int tt = dir ? 15 - t : t;
    for (int e = tid; e < 1024; e += 256)
      xt[e] = hc[((size_t)(n0 + (e >> 7)) * 16 + tt) * 128 + (e & 127)];
    __syncthreads();
    float acc[4][8];
    #pragma unroll
    for (int j = 0; j < 4; ++j)
      #pragma unroll
      for (int s = 0; s < 8; ++s) acc[j][s] = bias[j];
    for (int k = 0; k < 128; ++k) {
      float4 w = wi4[k * 256 + tid];
      #pragma unroll
      for (int s = 0; s < 8; ++s) {
        float xv = xt[s * 128 + k];
        acc[0][s] += w.x * xv; acc[1][s] += w.y * xv;
        acc[2][s] += w.z * xv; acc[3][s] += w.w * xv;
      }
    }
    for (int k = 0; k < 256; ++k) {
      float4 w = wh4[k * 256 + tid];
      #pragma unroll
      for (int s = 0; s < 8; ++s) {
        float hv = hsh[s * 256 + k];
        acc[0][s] += w.x * hv; acc[1][s] += w.y * hv;
        acc[2][s] += w.z * hv; acc[3][s] += w.w * hv;
      }
    }
    #pragma unroll
    for (int j = 0; j < 4; ++j)
      #pragma unroll
      for (int s = 0; s < 8; ++s)
        gbuf[s * 1024 + 4 * tid + j] = acc[j][s];
    __syncthreads();
    #pragma unroll
    for (int s = 0; s < 8; ++s) {
      float iv = gbuf[s * 1024 + tid];
      float fv = gbuf[s * 1024 + 256 + tid];
      float gv = gbuf[s * 1024 + 512 + tid];
      float ov = gbuf[s * 1024 + 768 + tid];
      float cn = sigf(fv) * csh[s * 256 + tid] + sigf(iv) * tanh_(gv);
      float hn = sigf(ov) * tanh_(cn);
      csh[s * 256 + tid] = cn;
      hsh[s * 256 + tid] = hn;
      yo[((size_t)(n0 + s) * 16 + tt) * 256 + tid] = hn;   // stored at ORIGINAL pos
    }
    __syncthreads();
  }
}

// ---------------- deconv(k=s=4) + bias + pad + residual ----------------
__global__ __launch_bounds__(256) void k_deconv(
    const float* __restrict__ yf, const float* __restrict__ yr,
    const float* __restrict__ dw, const float* __restrict__ db,
    const float* __restrict__ x32, float* __restrict__ intra) {
  __shared__ float hbi[8192];   // [16][512]
  int n = blockIdx.x, tid = threadIdx.x;
  for (int e = tid; e < 8192; e += 256) {
    int i = e >> 9, d = e & 511;
    hbi[e] = d < 256 ? yf[((size_t)n * 16 + i) * 256 + d]
                     : yr[((size_t)n * 16 + i) * 256 + d - 256];
  }
  __syncthreads();
  int op0 = tid, op1 = tid + 256;   // op = o*4 + m
  float acc0[16], acc1[16];
  #pragma unroll
  for (int i = 0; i < 16; ++i) { acc0[i] = 0.f; acc1[i] = 0.f; }
  for (int d = 0; d < 512; d += 2) {
    float w00 = dw[(size_t)d * 512 + op0];
    float w01 = dw[(size_t)d * 512 + op1];
    float w10 = dw[(size_t)(d + 1) * 512 + op0];
    float w11 = dw[(size_t)(d + 1) * 512 + op1];
    #pragma unroll
    for (int i = 0; i < 16; ++i) {
      float2 hv = *(const float2*)&hbi[i * 512 + d];
      acc0[i] += hv.x * w00 + hv.y * w10;
      acc1[i] += hv.x * w01 + hv.y * w11;
    }
  }
  int o0 = op0 >> 2, m0 = op0 & 3, o1 = op1 >> 2, m1 = op1 & 3;
  float db0 = db[o0], db1 = db[o1];
  #pragma unroll
  for (int i = 0; i < 16; ++i) {
    size_t i0 = ((size_t)n * 65 + i * 4 + m0) * 128 + o0;
    size_t i1 = ((size_t)n * 65 + i * 4 + m1) * 128 + o1;
    intra[i0] = acc0[i] + db0 + x32[i0];
    intra[i1] = acc1[i] + db1 + x32[i1];
  }
  if (tid < 128) {   // padded freq row 64: zeros + bias + residual
    size_t ip = ((size_t)n * 65 + 64) * 128 + tid;
    intra[ip] = db[tid] + x32[ip];
  }
}

// ---------------- LN over C + transpose to [B*NF][T][C] ----------------
__global__ __launch_bounds__(256) void k_ln1(
    const float* __restrict__ intra, const float* __restrict__ g1,
    const float* __restrict__ b1, float* __restrict__ out) {
  __shared__ float rs[4], rq[4];
  int n = blockIdx.x, tid = threadIdx.x;
  int gr = tid >> 7, o = tid & 127, wid = tid >> 6;
  int b = n >> 9, t = n & 511;
  float gv = g1[o], bv = b1[o];
  for (int f0 = 0; f0 < 65; f0 += 2) {
    int f = f0 + gr;
    bool ok = f < 65;
    float v = 0.f;
    if (ok) v = intra[((size_t)n * 65 + f) * 128 + o];
    float s = v, q = v * v;
    wavered2(s, q);
    if ((tid & 63) == 0) { rs[wid] = s; rq[wid] = q; }
    __syncthreads();
    if (ok) {
      float S = rs[2 * gr] + rs[2 * gr + 1], Q = rq[2 * gr] + rq[2 * gr + 1];
      float mu = S / 128.f;
      float rinv = rsqrtf(fmaxf(Q / 128.f - mu * mu, 0.f) + 1e-5f);
      out[((size_t)(b * 65 + f) * 512 + t) * 128 + o] = (v - mu) * rinv * gv + bv;
    }
    __syncthreads();
  }
}

// ---------------- inter causal LSTM over time + fused Linear + residual ----
// 17 blocks x 512 threads (8 waves), 16 seqs/block, MFMA 16x16x32 bf16.
// A = [x(128);h(256)] hi+lo bf16 frags in LDS (fragment order, conflict-free
// ds_read_b128, double-buffered). B = pre-swizzled weight frags from L2.
// Wave w owns gate cols [32w,32w+32) of i/f/g/o -> nonlin + c-state in regs.
// One __syncthreads per timestep; fused Linear = 8 MFMA/wave on h frags.
__global__ __launch_bounds__(512, 2) void k_inter_lstm(
    const float* __restrict__ ln1y,
    const u16* __restrict__ gfrag, const u16* __restrict__ lfrag,
    const float* __restrict__ bih, const float* __restrict__ bhh,
    const float* __restrict__ lb,
    const float* __restrict__ h0a, const float* __restrict__ c0a,
    const float* __restrict__ intra, float* __restrict__ inter) {
  __shared__ __align__(16) u16 Ahi[2][6144];   // [buf][kc*512 + lane*8 + j]
  __shared__ __align__(16) u16 Alo[2][6144];   // kc 0..3 = x, 4..11 = h
  int tid = threadIdx.x;
  int w = tid >> 6, l = tid & 63;
  int n0 = blockIdx.x * 16;
  int r0 = (l >> 4) << 2;        // acc row (seq) base
  int cl = l & 15;               // col-in-tile

  // ---- x-stage mapping: thread covers 4 consecutive k of one frag slot ----
  int skc  = tid >> 7;                        // 0..3
  int sl   = (tid & 127) >> 1;                // frag lane-slot 0..63
  int sj   = (tid & 1) << 2;                  // j base 0 or 4
  int srow = sl & 15;
  int sk   = skc * 32 + ((sl >> 4) << 3) + sj;
  int sseq = n0 + srow;
  bool sok = sseq < 260;
  const float4* xsrc =
      (const float4*)(ln1y + (size_t)(sok ? sseq : 0) * 65536 + sk);
  int sdst = skc * 512 + sl * 8 + sj;

  // ---- per-lane biases ----
  float bsum[4][2];
  #pragma unroll
  for (int g = 0; g < 4; ++g)
    #pragma unroll
    for (int m = 0; m < 2; ++m) {
      int col = 256 * g + 32 * w + 16 * m + cl;
      bsum[g][m] = bih[col] + bhh[col];
    }
  float lbv = lb[16 * w + cl];

  // ---- residual/output addressing (seq fixed per lane) ----
  bool rok[4];
  size_t rbase[4];
  #pragma unroll
  for (int reg = 0; reg < 4; ++reg) {
    int seq = n0 + r0 + reg;
    rok[reg] = seq < 260;
    int sq = rok[reg] ? seq : 0;
    int b_ = sq / 65, f_ = sq - b_ * 65;
    rbase[reg] = ((size_t)b_ * 512 * 65 + f_) * 128 + 16 * w + cl;
  }

  // ---- c-state init + h0 -> frag buf0 ----
  float cst[2][4];
  #pragma unroll
  for (int m = 0; m < 2; ++m) {
    int col = 32 * w + 16 * m + cl;
    #pragma unroll
    for (int reg = 0; reg < 4; ++reg) {
      int seq = n0 + r0 + reg;
      float c0v_ = (seq < 260) ? c0a[(size_t)seq * 256 + col] : 0.f;
      float h0v_ = (seq < 260) ? h0a[(size_t)seq * 256 + col] : 0.f;
      cst[m][reg] = c0v_;
      u16 hh = f2b(h0v_);
      u16 hl = f2b(h0v_ - b2f(hh));
      int idx = (4 + w) * 512 + ((r0 + reg) + 16 * (2 * m + (cl >> 3))) * 8 + (l & 7);
      Ahi[0][idx] = hh; Alo[0][idx] = hl;
    }
  }
  // ---- x_0 -> frag buf0 ----
  {
    float4 xv = sok ? xsrc[0] : make_float4(0.f, 0.f, 0.f, 0.f);
    u16 a0 = f2b(xv.x), a1 = f2b(xv.y), a2 = f2b(xv.z), a3 = f2b(xv.w);
    u16 c0_ = f2b(xv.x - b2f(a0)), c1_ = f2b(xv.y - b2f(a1)),
        c2_ = f2b(xv.z - b2f(a2)), c3_ = f2b(xv.w - b2f(a3));
    *(uint2*)&Ahi[0][sdst] =
        make_uint2((u32)a0 | ((u32)a1 << 16), (u32)a2 | ((u32)a3 << 16));
    *(uint2*)&Alo[0][sdst] =
        make_uint2((u32)c0_ | ((u32)c1_ << 16), (u32)c2_ | ((u32)c3_ << 16));
  }
  __syncthreads();

  for (int t = 0; t < 512; ++t) {
    const u16* phi = Ahi[t & 1];
    const u16* plo = Alo[t & 1];
    u16* qhi = Ahi[(t + 1) & 1];
    u16* qlo = Alo[(t + 1) & 1];
    // issue next-x + residual loads early; consumed after the MFMA phase
    int tn = t < 511 ? t + 1 : 511;
    float4 xv = sok ? xsrc[(size_t)tn * 32] : make_float4(0.f, 0.f, 0.f, 0.f);
    float rsd[4];
    #pragma unroll
    for (int reg = 0; reg < 4; ++reg)
      rsd[reg] = rok[reg]
          ? __builtin_nontemporal_load(&intra[rbase[reg] + (size_t)t * 8320])
          : 0.f;

    // ---- gates: D[16 seqs][1024] = A_hi*W + A_lo*W + bias ----
    f32x4 acc[4][2];
    #pragma unroll
    for (int g = 0; g < 4; ++g)
      #pragma unroll
      for (int m = 0; m < 2; ++m)
        acc[g][m] = (f32x4){bsum[g][m], bsum[g][m], bsum[g][m], bsum[g][m]};
    #pragma unroll 3
    for (int kc = 0; kc < 12; ++kc) {
      bf16x8 ah = *(const bf16x8*)&phi[kc * 512 + l * 8];
      bf16x8 al = *(const bf16x8*)&plo[kc * 512 + l * 8];
      #pragma unroll
      for (int g = 0; g < 4; ++g)
        #pragma unroll
        for (int m = 0; m < 2; ++m) {
          int nt = 16 * g + 2 * w + m;
          bf16x8 bw = *(const bf16x8*)&gfrag[(size_t)(nt * 12 + kc) * 512 + l * 8];
          acc[g][m] = __builtin_amdgcn_mfma_f32_16x16x32_bf16(ah, bw, acc[g][m], 0, 0, 0);
          acc[g][m] = __builtin_amdgcn_mfma_f32_16x16x32_bf16(al, bw, acc[g][m], 0, 0, 0);
        }
    }
    // ---- nonlinearity + state update (in regs) + h_t -> next buf ----
    #pragma unroll
    for (int m = 0; m < 2; ++m) {
      #pragma unroll
      for (int reg = 0; reg < 4; ++reg) {
        float iv = acc[0][m][reg], fv = acc[1][m][reg];
        float gv = acc[2][m][reg], ov = acc[3][m][reg];
        float cn = sigf(fv) * cst[m][reg] + sigf(iv) * tanh_(gv);
        float hn = sigf(ov) * tanh_(cn);
        cst[m][reg] = cn;
        u16 hh = f2b(hn);
        u16 hl = f2b(hn - b2f(hh));
        int idx = (4 + w) * 512 + ((r0 + reg) + 16 * (2 * m + (cl >> 3))) * 8 + (l & 7);
        qhi[idx] = hh; qlo[idx] = hl;
      }
    }
    // ---- x_{t+1} -> next buf ----
    {
      u16 a0 = f2b(xv.x), a1 = f2b(xv.y), a2 = f2b(xv.z), a3 = f2b(xv.w);
      u16 c0_ = f2b(xv.x - b2f(a0)), c1_ = f2b(xv.y - b2f(a1)),
          c2_ = f2b(xv.z - b2f(a2)), c3_ = f2b(xv.w - b2f(a3));
      *(uint2*)&qhi[sdst] =
          make_uint2((u32)a0 | ((u32)a1 << 16), (u32)a2 | ((u32)a3 << 16));
      *(uint2*)&qlo[sdst] =
          make_uint2((u32)c0_ | ((u32)c1_ << 16), (u32)c2_ | ((u32)c3_ << 16));
    }
    __syncthreads();
    // ---- fused Linear from just-written h frags + residual store ----
    f32x4 lacc = (f32x4){0.f, 0.f, 0.f, 0.f};
    #pragma unroll
    for (int kc = 0; kc < 8; ++kc) {
      bf16x8 ah = *(const bf16x8*)&qhi[(4 + kc) * 512 + l * 8];
      bf16x8 bw = *(const bf16x8*)&lfrag[(size_t)(w * 8 + kc) * 512 + l * 8];
      lacc = __builtin_amdgcn_mfma_f32_16x16x32_bf16(ah, bw, lacc, 0, 0, 0);
    }
    #pragma unroll
    for (int reg = 0; reg < 4; ++reg)
      if (rok[reg])
        __builtin_nontemporal_store(lacc[reg] + lbv + rsd[reg],
                                    &inter[rbase[reg] + (size_t)t * 8320]);
    // next-iter reads go to the other buffer; single barrier per step is safe
  }
}

// ---------------- Q/K/V projections + PReLU (pre-LN) ----------------
__global__ __launch_bounds__(256) void k_qkv(
    const float* __restrict__ inter,
    const float* __restrict__ qw, const float* __restrict__ qb, const float* __restrict__ qa,
    const float* __restrict__ kw, const float* __restrict__ kb, const float* __restrict__ ka,
    const float* __restrict__ vw, const float* __restrict__ vb, const float* __restrict__ va,
    float* __restrict__ Qh, float* __restrict__ Kh, float* __restrict__ Vh) {
  __shared__ float xsl[8320];
  int n = blockIdx.x, tid = threadIdx.x;
  int b = n >> 9, t = n & 511;
  for (int e = tid; e < 8320; e += 256) xsl[e] = inter[(size_t)n * 8320 + e];
  __syncthreads();
  if (tid >= 192) return;
  const float* wrow; float bias, a; float* dst; int dsz;
  if (tid < 32) {
    wrow = qw + (size_t)tid * 128; bias = qb[tid]; a = qa[0];
    dst = Qh + ((size_t)(b * 4 + (tid >> 3)) * 512 + t) * 520 + (tid & 7); dsz = 8;
  } else if (tid < 64) {
    int d = tid - 32;
    wrow = kw + (size_t)d * 128; bias = kb[d]; a = ka[0];
    dst = Kh + ((size_t)(b * 4 + (d >> 3)) * 512 + t) * 520 + (d & 7); dsz = 8;
  } else {
    int d = tid - 64;
    wrow = vw + (size_t)d * 128; bias = vb[d]; a = va[0];
    dst = Vh + ((size_t)(b * 4 + (d >> 5)) * 512 + t) * 2080 + (d & 31); dsz = 32;
  }
  const float4* w4 = (const float4*)wrow;
  for (int f = 0; f < 65; ++f) {
    float acc = bias;
    const float4* xr = (const float4*)&xsl[f * 128];
    #pragma unroll
    for (int kk = 0; kk < 32; ++kk) {
      float4 w = w4[kk], xv = xr[kk];
      acc += w.x * xv.x + w.y * xv.y + w.z * xv.z + w.w * xv.w;
    }
    acc = acc >= 0.f ? acc : a * acc;
    dst[(size_t)f * dsz] = acc;
  }
}

// ---------------- LN over last dim (in-place) ----------------
__global__ __launch_bounds__(256) void k_lnrow(
    float* __restrict__ buf, int len,
    const float* __restrict__ g, const float* __restrict__ b) {
  __shared__ float rs[4], rq[4];
  int row = blockIdx.x, tid = threadIdx.x;
  float* p = buf + (size_t)row * len;
  float s = 0.f, q = 0.f;
  for (int e = tid; e < len; e += 256) { float v = p[e]; s += v; q += v * v; }
  wavered2(s, q);
  if ((tid & 63) == 0) { rs[tid >> 6] = s; rq[tid >> 6] = q; }
  __syncthreads();
  float S = rs[0] + rs[1] + rs[2] + rs[3];
  float Q = rq[0] + rq[1] + rq[2] + rq[3];
  float mu = S / len;
  float rinv = rsqrtf(fmaxf(Q / len - mu * mu, 0.f) + 1e-5f);
  for (int e = tid; e < len; e += 256) {
    float v = p[e];
    p[e] = (v - mu) * rinv * g[e] + b[e];
  }
}

// ---------------- windowed causal attention (100 keys) ----------------
__global__ __launch_bounds__(256) void k_attn(
    const float* __restrict__ Qh, const float* __restrict__ Kh,
    const float* __restrict__ Vh, const float* __restrict__ Kbuf,
    const float* __restrict__ Vbuf, float* __restrict__ av) {
  __shared__ float qrow[520], sc[100], red[2];
  int bid = blockIdx.x, tid = threadIdx.x;
  int bh = bid >> 9, t = bid & 511;
  for (int e = tid; e < 520; e += 256)
    qrow[e] = Qh[((size_t)bh * 512 + t) * 520 + e];
  __syncthreads();
  if (tid < 100) {
    int s = t + tid;
    float acc = 0.f;
    if (s < 99) {
      const float* kr = Kbuf + ((size_t)bh * 99 + s) * 520;
      for (int e = 0; e < 520; ++e) acc += qrow[e] * kr[e];
    } else {
      const float* kr = Kh + ((size_t)bh * 512 + (s - 99)) * 520;
      for (int e = 0; e < 520; ++e) acc += qrow[e] * kr[e];
    }
    sc[tid] = acc * 0.04385290096535147f;   // 1/sqrt(520)
  }
  __syncthreads();
  if (tid == 0) {
    float m = sc[0];
    for (int k = 1; k < 100; ++k) m = fmaxf(m, sc[k]);
    red[0] = m;
  }
  __syncthreads();
  if (tid < 100) sc[tid] = __expf(sc[tid] - red[0]);
  __syncthreads();
  if (tid == 0) {
    float s = 0.f;
    for (int k = 0; k < 100; ++k) s += sc[k];
    red[1] = 1.f / s;
  }
  __syncthreads();
  float rscale = red[1];
  int b = bh >> 2, nh = bh & 3;
  int kb = t < 99 ? 99 - t : 0;
  for (int o = tid; o < 2080; o += 256) {
    float acc = 0.f;
    for (int k = 0; k < kb; ++k)
      acc += sc[k] * Vbuf[((size_t)bh * 99 + t + k) * 2080 + o];
    for (int k = kb; k < 100; ++k)
      acc += sc[k] * Vh[((size_t)bh * 512 + (t + k - 99)) * 2080 + o];
    int f = o >> 5, vd = o & 31;
    av[((size_t)(b * 512 + t) * 65 + f) * 128 + nh * 32 + vd] = acc * rscale;
  }
}

// ---------------- P projection + PReLU ----------------
__global__ __launch_bounds__(256) void k_pproj(
    const float* __restrict__ av, const float* __restrict__ pw,
    const float* __restrict__ pb, const float* __restrict__ pa,
    float* __restrict__ ph) {
  __shared__ float avs[8320];
  int n = blockIdx.x, tid = threadIdx.x;
  for (int e = tid; e < 8320; e += 256) avs[e] = av[(size_t)n * 8320 + e];
  __syncthreads();
  int o = tid & 127, g = tid >> 7;
  float a = pa[0], bias = pb[o];
  const float4* w4 = (const float4*)(pw + (size_t)o * 128);
  for (int f = g; f < 65; f += 2) {
    float acc = bias;
    const float4* xr = (const float4*)&avs[f * 128];
    #pragma unroll
    for (int kk = 0; kk < 32; ++kk) {
      float4 w = w4[kk], xv = xr[kk];
      acc += w.x * xv.x + w.y * xv.y + w.z * xv.z + w.w * xv.w;
    }
    acc = acc >= 0.f ? acc : a * acc;
    ph[(size_t)n * 8320 + f * 128 + o] = acc;
  }
}

// ---------------- final LN(8320) + residual -> fp32 out ----------------
__global__ __launch_bounds__(256) void k_lnfinal(
    const float* __restrict__ ph, const float* __restrict__ plg,
    const float* __restrict__ plb, const float* __restrict__ inter,
    float* __restrict__ out) {
  __shared__ float rs[4], rq[4];
  int n = blockIdx.x, tid = threadIdx.x;
  const float* p = ph + (size_t)n * 8320;
  float s = 0.f, q = 0.f;
  for (int e = tid; e < 8320; e += 256) { float v = p[e]; s += v; q += v * v; }
  wavered2(s, q);
  if ((tid & 63) == 0) { rs[tid >> 6] = s; rq[tid >> 6] = q; }
  __syncthreads();
  float S = rs[0] + rs[1] + rs[2] + rs[3];
  float Q = rq[0] + rq[1] + rq[2] + rq[3];
  float mu = S / 8320.f;
  float rinv = rsqrtf(fmaxf(Q / 8320.f - mu * mu, 0.f) + 1e-5f);
  for (int e = tid; e < 8320; e += 256) {
    out[(size_t)n * 8320 + e] =
        (p[e] - mu) * rinv * plg[e] + plb[e] + inter[(size_t)n * 8320 + e];
  }
}

extern "C" void kernel_launch(void* const* d_in, const int* in_sizes, int n_in,
                              void* d_out, int out_size, void* d_ws, size_t ws_size,
                              hipStream_t stream) {
  const float* x       = (const float*)d_in[0];
  const float* conv_w  = (const float*)d_in[1];
  const float* conv_b  = (const float*)d_in[2];
  const float* conv_a  = (const float*)d_in[3];
  const float* ln0_g   = (const float*)d_in[4];
  const float* ln0_b   = (const float*)d_in[5];
  const float* iwih_f  = (const float*)d_in[6];
  const float* iwhh_f  = (const float*)d_in[7];
  const float* ibih_f  = (const float*)d_in[8];
  const float* ibhh_f  = (const float*)d_in[9];
  const float* iwih_r  = (const float*)d_in[10];
  const float* iwhh_r  = (const float*)d_in[11];
  const float* ibih_r  = (const float*)d_in[12];
  const float* ibhh_r  = (const float*)d_in[13];
  const float* deconv_w= (const float*)d_in[14];
  const float* deconv_b= (const float*)d_in[15];
  const float* ln1_g   = (const float*)d_in[16];
  const float* ln1_b   = (const float*)d_in[17];
  const float* wih     = (const float*)d_in[18];
  const float* whh     = (const float*)d_in[19];
  const float* bih     = (const float*)d_in[20];
  const float* bhh     = (const float*)d_in[21];
  const float* lin_w   = (const float*)d_in[22];
  const float* lin_b   = (const float*)d_in[23];
  const float* q_w     = (const float*)d_in[24];
  const float* q_b     = (const float*)d_in[25];
  const float* q_a     = (const float*)d_in[26];
  const float* q_lg    = (const float*)d_in[27];
  const float* q_lb    = (const float*)d_in[28];
  const float* k_w     = (const float*)d_in[29];
  const float* k_b     = (const float*)d_in[30];
  const float* k_a     = (const float*)d_in[31];
  const float* k_lg    = (const float*)d_in[32];
  const float* k_lb    = (const float*)d_in[33];
  const float* v_w     = (const float*)d_in[34];
  const float* v_b     = (const float*)d_in[35];
  const float* v_a     = (const float*)d_in[36];
  const float* v_lg    = (const float*)d_in[37];
  const float* v_lb    = (const float*)d_in[38];
  const float* p_w     = (const float*)d_in[39];
  const float* p_b     = (const float*)d_in[40];
  const float* p_a     = (const float*)d_in[41];
  const float* p_lg    = (const float*)d_in[42];
  const float* p_lb    = (const float*)d_in[43];
  const float* K_buf   = (const float*)d_in[44];
  const float* V_buf   = (const float*)d_in[45];
  const float* h0v     = (const float*)d_in[46];
  const float* c0v     = (const float*)d_in[47];

  char* ws = (char*)d_ws;
  float* hc    = (float*)(ws + OFF_A);
  float* yfb   = (float*)(ws + OFF_A + 16777216ULL);
  float* yrb   = (float*)(ws + OFF_DE);
  float* ln1y  = (float*)(ws + OFF_A);
  float* Vh    = (float*)(ws + OFF_A);
  float* phb   = (float*)(ws + OFF_A);
  float* intra = (float*)(ws + OFF_B);
  float* avb   = (float*)(ws + OFF_B);
  float* inter = (float*)(ws + OFF_C);
  float* Qh    = (float*)(ws + OFF_DE);
  float* Kh    = (float*)(ws + OFF_DE + 17039360ULL);
  float* wT    = (float*)(ws + OFF_WT);
  float* wiTf = wT + 0;        // 131072 floats
  float* whTf = wT + 131072;   // 262144
  float* wiTr = wT + 393216;   // 131072
  float* whTr = wT + 524288;   // 262144 -> ends at 786432 floats (3 MB)
  u16* gfragW = (u16*)(wT + 786432);    // 393216 u16 (768 KB) gate-weight frags
  u16* lfragW = gfragW + 393216;        // 32768 u16 (64 KB) lin-weight frags

  k_transpose_ff<<<512, 256, 0, stream>>>(iwih_f, wiTf, 1024, 128);
  k_transpose_ff<<<1024, 256, 0, stream>>>(iwhh_f, whTf, 1024, 256);
  k_transpose_ff<<<512, 256, 0, stream>>>(iwih_r, wiTr, 1024, 128);
  k_transpose_ff<<<1024, 256, 0, stream>>>(iwhh_r, whTr, 1024, 256);
  k_prep_gfrag<<<1536, 256, 0, stream>>>(wih, whh, gfragW);
  k_prep_lfrag<<<128, 256, 0, stream>>>(lin_w, lfragW);

  k_conv_ln0<<<2048, 256, 0, stream>>>(x, conv_w, conv_b, conv_a, ln0_g, ln0_b, hc);
  k_intra_lstm<<<512, 256, 0, stream>>>(hc, wiTf, whTf, ibih_f, ibhh_f,
                                        wiTr, whTr, ibih_r, ibhh_r, yfb, yrb);
  k_deconv<<<2048, 256, 0, stream>>>(yfb, yrb, deconv_w, deconv_b, x, intra);
  k_ln1<<<2048, 256, 0, stream>>>(intra, ln1_g, ln1_b, ln1y);
  k_inter_lstm<<<17, 512, 0, stream>>>(ln1y, gfragW, lfragW, bih, bhh,
                                       lin_b, h0v, c0v, intra, inter);
  k_qkv<<<2048, 256, 0, stream>>>(inter, q_w, q_b, q_a, k_w, k_b, k_a,
                                  v_w, v_b, v_a, Qh, Kh, Vh);
  k_lnrow<<<8192, 256, 0, stream>>>(Qh, 520, q_lg, q_lb);
  k_lnrow<<<8192, 256, 0, stream>>>(Kh, 520, k_lg, k_lb);
  k_lnrow<<<8192, 256, 0, stream>>>(Vh, 2080, v_lg, v_lb);
  k_attn<<<8192, 256, 0, stream>>>(Qh, Kh, Vh, K_buf, V_buf, avb);
  k_pproj<<<2048, 256, 0, stream>>>(avb, p_w, p_b, p_a, phb);
  k_lnfinal<<<2048, 256, 0, stream>>>(phb, p_lg, p_lb, inter, (float*)d_out);
}